// Round 1
// baseline (207.949 us; speedup 1.0000x reference)
//
#include <hip/hip_runtime.h>
#include <cstdint>
#include <cstddef>

#define NCH 128
#define SCAN_CHUNK 2048  // 256 threads x 8 elems
#define GEMM_ROWS 64
#define XPAD 136         // 128 + 8 bf16 pad: A-frag ds_read_b128 conflict-free

typedef short bf16x8 __attribute__((ext_vector_type(8)));
typedef float f32x4 __attribute__((ext_vector_type(4)));

__device__ __forceinline__ int detect_is64(const unsigned int* __restrict__ ei) {
  // int64 edge_index with ids < 2^31 -> all odd 32-bit words zero. Wave-uniform;
  // call with all lanes active (kernel top, before divergence).
  unsigned int v = ei[((threadIdx.x & 63) << 1) + 1];
  return (__ballot(v != 0u) == 0ULL) ? 1 : 0;
}

__device__ __forceinline__ unsigned short f2bf(float x) {
  unsigned int u = __float_as_uint(x);
  u += 0x7fffu + ((u >> 16) & 1u);  // RNE
  return (unsigned short)(u >> 16);
}

__device__ __forceinline__ int ei_at(const void* ei, long long i, int is64) {
  return is64 ? (int)((const long long*)ei)[i] : ((const int*)ei)[i];
}

// K1: blocks [0,gbl) = MFMA GEMM g[i,:] = bf16(x@W) (UNSCALED - dis folded into
// k_agg's FMA, so the GEMM no longer depends on count/scan). B-fragments are
// gathered directly from f32 W (64KB, L2-hot after first blocks) - no wt buffer.
// Blocks [gbl,..) = degree count (plain atomicAdd, no rank). The two halves
// co-run: GEMM's MFMA/BW hides count's atomic latency.
__global__ __launch_bounds__(256) void k_gemm_count(
    const float* __restrict__ x, const float* __restrict__ W,
    unsigned short* __restrict__ g, int N, const void* __restrict__ ei, int E,
    int* __restrict__ counts, int gbl) {
  if ((int)blockIdx.x >= gbl) {
    int is64 = detect_is64((const unsigned int*)ei);
    int e = (blockIdx.x - gbl) * 256 + threadIdx.x;
    if (e < E) atomicAdd(&counts[ei_at(ei, (long long)E + e, is64)], 1);
    return;
  }
  __shared__ unsigned short xbf[GEMM_ROWS * XPAD];
  int t = threadIdx.x;
  int row0 = blockIdx.x * GEMM_ROWS;
#pragma unroll
  for (int j = 0; j < 8; ++j) {
    int idx = t + 256 * j;
    int r = idx >> 5, ch = idx & 31;
    int row = row0 + r;
    float4 v = (row < N) ? ((const float4*)(x + (size_t)row * NCH))[ch]
                         : make_float4(0.f, 0.f, 0.f, 0.f);
    ushort4 p;
    p.x = f2bf(v.x); p.y = f2bf(v.y); p.z = f2bf(v.z); p.w = f2bf(v.w);
    *(ushort4*)&xbf[r * XPAD + ch * 4] = p;
  }
  int lane = t & 63, wv = t >> 6;
  int n0 = wv * 32, l15 = lane & 15, q = lane >> 4;
  // B operand: wt[n][k] = W[k][n], gathered per-lane from global W. 64 scalar
  // L2-hit loads per lane, issued before the barrier so they overlap staging.
  bf16x8 B[4][2];
#pragma unroll
  for (int ks = 0; ks < 4; ++ks)
#pragma unroll
    for (int nt = 0; nt < 2; ++nt) {
      int n = n0 + nt * 16 + l15;
      bf16x8 b;
#pragma unroll
      for (int j = 0; j < 8; ++j)
        b[j] = (short)f2bf(W[(size_t)(ks * 32 + q * 8 + j) * NCH + n]);
      B[ks][nt] = b;
    }
  __syncthreads();
  f32x4 acc[4][2];
#pragma unroll
  for (int mt = 0; mt < 4; ++mt)
#pragma unroll
    for (int nt = 0; nt < 2; ++nt)
#pragma unroll
      for (int i = 0; i < 4; ++i) acc[mt][nt][i] = 0.f;
#pragma unroll
  for (int ks = 0; ks < 4; ++ks) {
#pragma unroll
    for (int mt = 0; mt < 4; ++mt) {
      bf16x8 a = *(const bf16x8*)&xbf[(mt * 16 + l15) * XPAD + ks * 32 + q * 8];
      acc[mt][0] = __builtin_amdgcn_mfma_f32_16x16x32_bf16(a, B[ks][0], acc[mt][0], 0, 0, 0);
      acc[mt][1] = __builtin_amdgcn_mfma_f32_16x16x32_bf16(a, B[ks][1], acc[mt][1], 0, 0, 0);
    }
  }
#pragma unroll
  for (int mt = 0; mt < 4; ++mt) {
#pragma unroll
    for (int reg = 0; reg < 4; ++reg) {
      int rl = mt * 16 + q * 4 + reg;
      int row = row0 + rl;
      if (row < N) {
        size_t base = (size_t)row * NCH + n0;
        g[base + l15]      = f2bf(acc[mt][0][reg]);
        g[base + 16 + l15] = f2bf(acc[mt][1][reg]);
      }
    }
  }
}

// Single-pass exclusive scan (decoupled lookback): row_ptr[i+1],
// dis[i] = rsqrt(deg+1). Also RE-ZEROES counts so k_fill can reuse it as the
// per-dst fill cursor (replaces the rank array: -6.4MB of traffic).
__global__ __launch_bounds__(256) void k_scan(int* __restrict__ counts, int N,
                                              unsigned long long* __restrict__ flagsum,
                                              int* __restrict__ row_ptr,
                                              float* __restrict__ dis) {
  int t = threadIdx.x;
  int base = blockIdx.x * SCAN_CHUNK + t * 8;
  int v[8];
  int s = 0;
  if (base + 8 <= N) {
    const int4* p = (const int4*)(counts + base);
    int4 a = p[0], b = p[1];
    v[0] = a.x; v[1] = a.y; v[2] = a.z; v[3] = a.w;
    v[4] = b.x; v[5] = b.y; v[6] = b.z; v[7] = b.w;
  } else {
#pragma unroll
    for (int j = 0; j < 8; ++j) {
      int i = base + j;
      v[j] = (i < N) ? counts[i] : 0;
    }
  }
#pragma unroll
  for (int j = 0; j < 8; ++j) s += v[j];
  int lane = t & 63, w = t >> 6;
  int incl = s;
#pragma unroll
  for (int off = 1; off < 64; off <<= 1) {
    int o = __shfl_up(incl, off);
    if (lane >= off) incl += o;
  }
  __shared__ int wsum[4];
  __shared__ int s_boff;
  if (lane == 63) wsum[w] = incl;
  __syncthreads();
  if (t == 0) {
    int btot = (wsum[0] + wsum[1]) + (wsum[2] + wsum[3]);
    unsigned long long pub = (1ull << 63) | (unsigned int)btot;
    __hip_atomic_store(&flagsum[blockIdx.x], pub, __ATOMIC_RELEASE,
                       __HIP_MEMORY_SCOPE_AGENT);
    int acc = 0;
    for (int i = (int)blockIdx.x - 1; i >= 0; --i) {
      unsigned long long fv;
      do {
        fv = __hip_atomic_load(&flagsum[i], __ATOMIC_ACQUIRE,
                               __HIP_MEMORY_SCOPE_AGENT);
      } while (!(fv >> 63));
      acc += (int)(unsigned int)fv;
    }
    s_boff = acc;
  }
  __syncthreads();
  int woff = 0;
#pragma unroll
  for (int k = 0; k < 4; ++k)
    if (k < w) woff += wsum[k];
  int run = s_boff + woff + (incl - s);
#pragma unroll
  for (int j = 0; j < 8; ++j) {
    run += v[j];
    int i = base + j;
    if (i < N) {
      row_ptr[i + 1] = run;
      dis[i] = rsqrtf((float)(v[j] + 1));  // +1 self-loop; always > 0
    }
  }
  // zero counts for reuse as the fill cursor (consumed above into v[])
  if (base + 8 <= N) {
    int4 z = make_int4(0, 0, 0, 0);
    int4* p = (int4*)(counts + base);
    p[0] = z; p[1] = z;
  } else {
#pragma unroll
    for (int j = 0; j < 8; ++j) {
      int i = base + j;
      if (i < N) counts[i] = 0;
    }
  }
  if (blockIdx.x == 0 && t == 0) row_ptr[0] = 0;
}

// K3: CSR fill. Rank recomputed via atomicAdd on the re-zeroed counts —
// same atomic count as before, no rank round-trip.
__global__ __launch_bounds__(256) void k_fill(const void* __restrict__ ei, int E,
                                              int* __restrict__ counts,
                                              const int* __restrict__ row_ptr,
                                              int* __restrict__ edge_src) {
  int is64 = detect_is64((const unsigned int*)ei);
  int e = blockIdx.x * 256 + threadIdx.x;
  if (e < E) {
    int s = ei_at(ei, e, is64);
    int d = ei_at(ei, (long long)E + e, is64);
    int r = atomicAdd(&counts[d], 1);
    edge_src[row_ptr[d] + r] = s;
  }
}

__device__ __forceinline__ void acc8(float* a, uint4 v, float w) {
  a[0] = fmaf(__uint_as_float(v.x << 16), w, a[0]);
  a[1] = fmaf(__uint_as_float(v.x & 0xffff0000u), w, a[1]);
  a[2] = fmaf(__uint_as_float(v.y << 16), w, a[2]);
  a[3] = fmaf(__uint_as_float(v.y & 0xffff0000u), w, a[3]);
  a[4] = fmaf(__uint_as_float(v.z << 16), w, a[4]);
  a[5] = fmaf(__uint_as_float(v.z & 0xffff0000u), w, a[5]);
  a[6] = fmaf(__uint_as_float(v.w << 16), w, a[6]);
  a[7] = fmaf(__uint_as_float(v.w & 0xffff0000u), w, a[7]);
}

// One wave per node, 4 groups of 16 lanes; group handles edges e+4j+grp, lane
// sl=L&15 -> channels [8sl,8sl+8) as uint4 (16B, coalescing sweet spot). Per
// wave-instruction: 4 edges x 256B. dis[src] is folded into the accumulate FMA
// (w = dis[s], 0 for masked tail slots), so g holds the UNSCALED xW.
__global__ __launch_bounds__(256) void k_agg(const unsigned short* __restrict__ g,
                                             const int* __restrict__ row_ptr,
                                             const int* __restrict__ edge_src,
                                             const float* __restrict__ dis,
                                             const float* __restrict__ bias,
                                             float* __restrict__ out, int N) {
  int i = blockIdx.x * 4 + (threadIdx.x >> 6);
  if (i >= N) return;
  int lane = threadIdx.x & 63;
  int grp = lane >> 4, sl = lane & 15;
  float a[8];
#pragma unroll
  for (int k = 0; k < 8; ++k) a[k] = 0.f;
  float di = dis[i];
  if (grp == 0) {  // self-loop: w = dis[i]; final *di gives dis^2
    uint4 v = *(const uint4*)(g + (size_t)i * NCH + sl * 8);
    acc8(a, v, di);
  }
  int e = row_ptr[i];
  int end = row_ptr[i + 1];
  for (; e + 16 <= end; e += 16) {
    int s[4];
#pragma unroll
    for (int j = 0; j < 4; ++j)
      s[j] = __builtin_nontemporal_load(edge_src + e + 4 * j + grp);
    uint4 v[4];
    float w[4];
#pragma unroll
    for (int j = 0; j < 4; ++j) {
      v[j] = *(const uint4*)(g + (size_t)s[j] * NCH + sl * 8);
      w[j] = dis[s[j]];
    }
#pragma unroll
    for (int j = 0; j < 4; ++j) acc8(a, v[j], w[j]);
  }
  // masked tail, 4 edges/iter: clamp index (duplicate row is a cache hit),
  // zero weight kills the contribution - no divergent remainder cascade.
  for (; e < end; e += 4) {
    int idx = e + grp;
    int cl = idx < end ? idx : end - 1;
    int s = __builtin_nontemporal_load(edge_src + cl);
    float w = (idx < end) ? dis[s] : 0.f;
    uint4 v = *(const uint4*)(g + (size_t)s * NCH + sl * 8);
    acc8(a, v, w);
  }
#pragma unroll
  for (int k = 0; k < 8; ++k) {
    a[k] += __shfl_xor(a[k], 16);
    a[k] += __shfl_xor(a[k], 32);
  }
  if (grp == 0) {
    const float4* bb = (const float4*)bias;
    float4 b0 = bb[sl * 2], b1 = bb[sl * 2 + 1];
    f32x4 o0, o1;
    o0[0] = fmaxf(fmaf(a[0], di, b0.x), 0.f);
    o0[1] = fmaxf(fmaf(a[1], di, b0.y), 0.f);
    o0[2] = fmaxf(fmaf(a[2], di, b0.z), 0.f);
    o0[3] = fmaxf(fmaf(a[3], di, b0.w), 0.f);
    o1[0] = fmaxf(fmaf(a[4], di, b1.x), 0.f);
    o1[1] = fmaxf(fmaf(a[5], di, b1.y), 0.f);
    o1[2] = fmaxf(fmaf(a[6], di, b1.z), 0.f);
    o1[3] = fmaxf(fmaf(a[7], di, b1.w), 0.f);
    float* op = out + (size_t)i * NCH + sl * 8;
    __builtin_nontemporal_store(o0, (f32x4*)op);
    __builtin_nontemporal_store(o1, (f32x4*)(op + 4));
  }
}

extern "C" void kernel_launch(void* const* d_in, const int* in_sizes, int n_in,
                              void* d_out, int out_size, void* d_ws, size_t ws_size,
                              hipStream_t stream) {
  const float* x    = (const float*)d_in[0];
  const void*  ei   = d_in[1];
  const float* W    = (const float*)d_in[2];
  const float* bias = (const float*)d_in[3];
  float* out = (float*)d_out;

  int N = out_size / NCH;       // 50000
  int E = in_sizes[1] / 2;      // 800000

  char* ws = (char*)d_ws;
  size_t off = 0;
  auto alloc = [&](size_t bytes) -> char* {
    char* p = ws + off;
    off = (off + bytes + 255) & ~(size_t)255;
    return p;
  };
  char* zbase = ws;  // zero region: counts + flagsum (one small memset)
  int*                counts   = (int*)alloc((size_t)N * 4);
  unsigned long long* flagsum  = (unsigned long long*)alloc(1024);
  size_t zbytes = off;
  int*                row_ptr  = (int*)alloc((size_t)(N + 1) * 4);
  float*              dis      = (float*)alloc((size_t)N * 4);
  int*                edge_src = (int*)alloc((size_t)E * 4);
  unsigned short*     g        = (unsigned short*)alloc((size_t)N * NCH * 2);
  (void)ws_size;

  int nb  = (N + SCAN_CHUNK - 1) / SCAN_CHUNK;  // 25
  int gbl = (N + GEMM_ROWS - 1) / GEMM_ROWS;    // 782 gemm blocks
  int cbl = (E + 255) / 256;                    // 3125 count/fill blocks

  (void)hipMemsetAsync(zbase, 0, zbytes, stream);
  k_gemm_count<<<gbl + cbl, 256, 0, stream>>>(x, W, g, N, ei, E, counts, gbl);
  k_scan<<<nb, 256, 0, stream>>>(counts, N, flagsum, row_ptr, dis);
  k_fill<<<cbl, 256, 0, stream>>>(ei, E, counts, row_ptr, edge_src);
  k_agg<<<(N + 3) / 4, 256, 0, stream>>>(g, row_ptr, edge_src, dis, bias, out, N);
}

// Round 2
// 174.782 us; speedup vs baseline: 1.1898x; 1.1898x over previous
//
#include <hip/hip_runtime.h>
#include <cstdint>
#include <cstddef>

#define NCH 128
#define SCAN_CHUNK 2048  // 256 threads x 8 elems
#define GEMM_ROWS 64
#define XPAD 136         // 128 + 8 bf16 pad: A-frag ds_read_b128 conflict-free

typedef short bf16x8 __attribute__((ext_vector_type(8)));
typedef float f32x4 __attribute__((ext_vector_type(4)));

__device__ __forceinline__ int detect_is64(const unsigned int* __restrict__ ei) {
  // int64 edge_index with ids < 2^31 -> all odd 32-bit words zero. Wave-uniform;
  // call with all lanes active (kernel top, before divergence).
  unsigned int v = ei[((threadIdx.x & 63) << 1) + 1];
  return (__ballot(v != 0u) == 0ULL) ? 1 : 0;
}

__device__ __forceinline__ unsigned short f2bf(float x) {
  unsigned int u = __float_as_uint(x);
  u += 0x7fffu + ((u >> 16) & 1u);  // RNE
  return (unsigned short)(u >> 16);
}

__device__ __forceinline__ int ei_at(const void* ei, long long i, int is64) {
  return is64 ? (int)((const long long*)ei)[i] : ((const int*)ei)[i];
}

// K1: blocks [0,gbl) = MFMA GEMM g[i,:] = bf16(x@W) (UNSCALED - dis folded into
// k_agg's FMA). Blocks [gbl,..) = degree count + rank, 4 edges/thread:
// vector int4 dst load -> 4 INDEPENDENT atomicAdds in flight (the R1 counters
// showed 1-op/thread edge passes are latency-bound: VALUBusy 0.6%, HBM 15%).
// GEMM co-runs and hides under the count's atomic latency.
__global__ __launch_bounds__(256) void k_gemm_count(
    const float* __restrict__ x, const float* __restrict__ W,
    unsigned short* __restrict__ g, int N, const void* __restrict__ ei, int E,
    int* __restrict__ counts, int* __restrict__ rank, int gbl) {
  if ((int)blockIdx.x >= gbl) {
    int is64 = detect_is64((const unsigned int*)ei);
    int base = ((int)blockIdx.x - gbl) * 1024 + (int)threadIdx.x * 4;
    if (base >= E) return;
    if (base + 4 <= E) {
      int d0, d1, d2, d3;
      if (is64) {
        const long long* p = (const long long*)ei + E + base;
        d0 = (int)p[0]; d1 = (int)p[1]; d2 = (int)p[2]; d3 = (int)p[3];
      } else {
        int4 v = *(const int4*)((const int*)ei + E + base);
        d0 = v.x; d1 = v.y; d2 = v.z; d3 = v.w;
      }
      int r0 = atomicAdd(&counts[d0], 1);
      int r1 = atomicAdd(&counts[d1], 1);
      int r2 = atomicAdd(&counts[d2], 1);
      int r3 = atomicAdd(&counts[d3], 1);
      *(int4*)(rank + base) = make_int4(r0, r1, r2, r3);
    } else {
      for (int j = 0; j < 4; ++j)
        if (base + j < E) {
          int dd = ei_at(ei, (long long)E + base + j, is64);
          rank[base + j] = atomicAdd(&counts[dd], 1);
        }
    }
    return;
  }
  __shared__ unsigned short xbf[GEMM_ROWS * XPAD];
  int t = threadIdx.x;
  int row0 = blockIdx.x * GEMM_ROWS;
#pragma unroll
  for (int j = 0; j < 8; ++j) {
    int idx = t + 256 * j;
    int r = idx >> 5, ch = idx & 31;
    int row = row0 + r;
    float4 v = (row < N) ? ((const float4*)(x + (size_t)row * NCH))[ch]
                         : make_float4(0.f, 0.f, 0.f, 0.f);
    ushort4 p;
    p.x = f2bf(v.x); p.y = f2bf(v.y); p.z = f2bf(v.z); p.w = f2bf(v.w);
    *(ushort4*)&xbf[r * XPAD + ch * 4] = p;
  }
  int lane = t & 63, wv = t >> 6;
  int n0 = wv * 32, l15 = lane & 15, q = lane >> 4;
  // B operand: wt[n][k] = W[k][n], gathered per-lane from global W (64KB,
  // L2-hot). Issued before the barrier so it overlaps the LDS staging.
  bf16x8 B[4][2];
#pragma unroll
  for (int ks = 0; ks < 4; ++ks)
#pragma unroll
    for (int nt = 0; nt < 2; ++nt) {
      int n = n0 + nt * 16 + l15;
      bf16x8 b;
#pragma unroll
      for (int j = 0; j < 8; ++j)
        b[j] = (short)f2bf(W[(size_t)(ks * 32 + q * 8 + j) * NCH + n]);
      B[ks][nt] = b;
    }
  __syncthreads();
  f32x4 acc[4][2];
#pragma unroll
  for (int mt = 0; mt < 4; ++mt)
#pragma unroll
    for (int nt = 0; nt < 2; ++nt)
#pragma unroll
      for (int i = 0; i < 4; ++i) acc[mt][nt][i] = 0.f;
#pragma unroll
  for (int ks = 0; ks < 4; ++ks) {
#pragma unroll
    for (int mt = 0; mt < 4; ++mt) {
      bf16x8 a = *(const bf16x8*)&xbf[(mt * 16 + l15) * XPAD + ks * 32 + q * 8];
      acc[mt][0] = __builtin_amdgcn_mfma_f32_16x16x32_bf16(a, B[ks][0], acc[mt][0], 0, 0, 0);
      acc[mt][1] = __builtin_amdgcn_mfma_f32_16x16x32_bf16(a, B[ks][1], acc[mt][1], 0, 0, 0);
    }
  }
#pragma unroll
  for (int mt = 0; mt < 4; ++mt) {
#pragma unroll
    for (int reg = 0; reg < 4; ++reg) {
      int rl = mt * 16 + q * 4 + reg;
      int row = row0 + rl;
      if (row < N) {
        size_t base = (size_t)row * NCH + n0;
        g[base + l15]      = f2bf(acc[mt][0][reg]);
        g[base + 16 + l15] = f2bf(acc[mt][1][reg]);
      }
    }
  }
}

// Single-pass exclusive scan (decoupled lookback): row_ptr[i+1],
// dis[i] = rsqrt(deg+1).
__global__ __launch_bounds__(256) void k_scan(const int* __restrict__ counts, int N,
                                              unsigned long long* __restrict__ flagsum,
                                              int* __restrict__ row_ptr,
                                              float* __restrict__ dis) {
  int t = threadIdx.x;
  int base = blockIdx.x * SCAN_CHUNK + t * 8;
  int v[8];
  int s = 0;
  if (base + 8 <= N) {
    const int4* p = (const int4*)(counts + base);
    int4 a = p[0], b = p[1];
    v[0] = a.x; v[1] = a.y; v[2] = a.z; v[3] = a.w;
    v[4] = b.x; v[5] = b.y; v[6] = b.z; v[7] = b.w;
  } else {
#pragma unroll
    for (int j = 0; j < 8; ++j) {
      int i = base + j;
      v[j] = (i < N) ? counts[i] : 0;
    }
  }
#pragma unroll
  for (int j = 0; j < 8; ++j) s += v[j];
  int lane = t & 63, w = t >> 6;
  int incl = s;
#pragma unroll
  for (int off = 1; off < 64; off <<= 1) {
    int o = __shfl_up(incl, off);
    if (lane >= off) incl += o;
  }
  __shared__ int wsum[4];
  __shared__ int s_boff;
  if (lane == 63) wsum[w] = incl;
  __syncthreads();
  if (t == 0) {
    int btot = (wsum[0] + wsum[1]) + (wsum[2] + wsum[3]);
    unsigned long long pub = (1ull << 63) | (unsigned int)btot;
    __hip_atomic_store(&flagsum[blockIdx.x], pub, __ATOMIC_RELEASE,
                       __HIP_MEMORY_SCOPE_AGENT);
    int acc = 0;
    for (int i = (int)blockIdx.x - 1; i >= 0; --i) {
      unsigned long long fv;
      do {
        fv = __hip_atomic_load(&flagsum[i], __ATOMIC_ACQUIRE,
                               __HIP_MEMORY_SCOPE_AGENT);
      } while (!(fv >> 63));
      acc += (int)(unsigned int)fv;
    }
    s_boff = acc;
  }
  __syncthreads();
  int woff = 0;
#pragma unroll
  for (int k = 0; k < 4; ++k)
    if (k < w) woff += wsum[k];
  int run = s_boff + woff + (incl - s);
#pragma unroll
  for (int j = 0; j < 8; ++j) {
    run += v[j];
    int i = base + j;
    if (i < N) {
      row_ptr[i + 1] = run;
      dis[i] = rsqrtf((float)(v[j] + 1));  // +1 self-loop; always > 0
    }
  }
  if (blockIdx.x == 0 && t == 0) row_ptr[0] = 0;
}

// K3: CSR fill, atomic-free (rank-based), 4 edges/thread. Per thread: 3 vector
// index loads + 4 independent row_ptr gathers (L2-hot 200KB) + 4 independent
// scatter stores -> ~8 memory ops in flight vs R1's single dependent chain.
__global__ __launch_bounds__(256) void k_fill(const void* __restrict__ ei, int E,
                                              const int* __restrict__ rank,
                                              const int* __restrict__ row_ptr,
                                              int* __restrict__ edge_src) {
  int is64 = detect_is64((const unsigned int*)ei);
  int base = ((int)blockIdx.x * 256 + (int)threadIdx.x) * 4;
  if (base >= E) return;
  if (base + 4 <= E) {
    int s0, s1, s2, s3, d0, d1, d2, d3;
    if (is64) {
      const long long* ps = (const long long*)ei + base;
      const long long* pd = (const long long*)ei + E + base;
      s0 = (int)ps[0]; s1 = (int)ps[1]; s2 = (int)ps[2]; s3 = (int)ps[3];
      d0 = (int)pd[0]; d1 = (int)pd[1]; d2 = (int)pd[2]; d3 = (int)pd[3];
    } else {
      int4 vs = *(const int4*)((const int*)ei + base);
      int4 vd = *(const int4*)((const int*)ei + E + base);
      s0 = vs.x; s1 = vs.y; s2 = vs.z; s3 = vs.w;
      d0 = vd.x; d1 = vd.y; d2 = vd.z; d3 = vd.w;
    }
    int4 r = *(const int4*)(rank + base);
    int o0 = row_ptr[d0] + r.x;
    int o1 = row_ptr[d1] + r.y;
    int o2 = row_ptr[d2] + r.z;
    int o3 = row_ptr[d3] + r.w;
    edge_src[o0] = s0;
    edge_src[o1] = s1;
    edge_src[o2] = s2;
    edge_src[o3] = s3;
  } else {
    for (int j = 0; j < 4; ++j)
      if (base + j < E) {
        int s = ei_at(ei, base + j, is64);
        int d = ei_at(ei, (long long)E + base + j, is64);
        edge_src[row_ptr[d] + rank[base + j]] = s;
      }
  }
}

__device__ __forceinline__ void acc8(float* a, uint4 v, float w) {
  a[0] = fmaf(__uint_as_float(v.x << 16), w, a[0]);
  a[1] = fmaf(__uint_as_float(v.x & 0xffff0000u), w, a[1]);
  a[2] = fmaf(__uint_as_float(v.y << 16), w, a[2]);
  a[3] = fmaf(__uint_as_float(v.y & 0xffff0000u), w, a[3]);
  a[4] = fmaf(__uint_as_float(v.z << 16), w, a[4]);
  a[5] = fmaf(__uint_as_float(v.z & 0xffff0000u), w, a[5]);
  a[6] = fmaf(__uint_as_float(v.w << 16), w, a[6]);
  a[7] = fmaf(__uint_as_float(v.w & 0xffff0000u), w, a[7]);
}

// One wave per node, 4 groups of 16 lanes; group handles edges e+4j+grp, lane
// sl=L&15 -> channels [8sl,8sl+8) as uint4 (16B, coalescing sweet spot). Per
// wave-instruction: 4 edges x 256B. dis[src] is folded into the accumulate FMA
// (w = dis[s], 0 for masked tail slots), so g holds the UNSCALED xW.
__global__ __launch_bounds__(256) void k_agg(const unsigned short* __restrict__ g,
                                             const int* __restrict__ row_ptr,
                                             const int* __restrict__ edge_src,
                                             const float* __restrict__ dis,
                                             const float* __restrict__ bias,
                                             float* __restrict__ out, int N) {
  int i = blockIdx.x * 4 + (threadIdx.x >> 6);
  if (i >= N) return;
  int lane = threadIdx.x & 63;
  int grp = lane >> 4, sl = lane & 15;
  float a[8];
#pragma unroll
  for (int k = 0; k < 8; ++k) a[k] = 0.f;
  float di = dis[i];
  if (grp == 0) {  // self-loop: w = dis[i]; final *di gives dis^2
    uint4 v = *(const uint4*)(g + (size_t)i * NCH + sl * 8);
    acc8(a, v, di);
  }
  int e = row_ptr[i];
  int end = row_ptr[i + 1];
  for (; e + 16 <= end; e += 16) {
    int s[4];
#pragma unroll
    for (int j = 0; j < 4; ++j)
      s[j] = __builtin_nontemporal_load(edge_src + e + 4 * j + grp);
    uint4 v[4];
    float w[4];
#pragma unroll
    for (int j = 0; j < 4; ++j) {
      v[j] = *(const uint4*)(g + (size_t)s[j] * NCH + sl * 8);
      w[j] = dis[s[j]];
    }
#pragma unroll
    for (int j = 0; j < 4; ++j) acc8(a, v[j], w[j]);
  }
  // masked tail, 4 edges/iter: clamp index (duplicate row is a cache hit),
  // zero weight kills the contribution - no divergent remainder cascade.
  for (; e < end; e += 4) {
    int idx = e + grp;
    int cl = idx < end ? idx : end - 1;
    int s = __builtin_nontemporal_load(edge_src + cl);
    float w = (idx < end) ? dis[s] : 0.f;
    uint4 v = *(const uint4*)(g + (size_t)s * NCH + sl * 8);
    acc8(a, v, w);
  }
#pragma unroll
  for (int k = 0; k < 8; ++k) {
    a[k] += __shfl_xor(a[k], 16);
    a[k] += __shfl_xor(a[k], 32);
  }
  if (grp == 0) {
    const float4* bb = (const float4*)bias;
    float4 b0 = bb[sl * 2], b1 = bb[sl * 2 + 1];
    f32x4 o0, o1;
    o0[0] = fmaxf(fmaf(a[0], di, b0.x), 0.f);
    o0[1] = fmaxf(fmaf(a[1], di, b0.y), 0.f);
    o0[2] = fmaxf(fmaf(a[2], di, b0.z), 0.f);
    o0[3] = fmaxf(fmaf(a[3], di, b0.w), 0.f);
    o1[0] = fmaxf(fmaf(a[4], di, b1.x), 0.f);
    o1[1] = fmaxf(fmaf(a[5], di, b1.y), 0.f);
    o1[2] = fmaxf(fmaf(a[6], di, b1.z), 0.f);
    o1[3] = fmaxf(fmaf(a[7], di, b1.w), 0.f);
    float* op = out + (size_t)i * NCH + sl * 8;
    __builtin_nontemporal_store(o0, (f32x4*)op);
    __builtin_nontemporal_store(o1, (f32x4*)(op + 4));
  }
}

extern "C" void kernel_launch(void* const* d_in, const int* in_sizes, int n_in,
                              void* d_out, int out_size, void* d_ws, size_t ws_size,
                              hipStream_t stream) {
  const float* x    = (const float*)d_in[0];
  const void*  ei   = d_in[1];
  const float* W    = (const float*)d_in[2];
  const float* bias = (const float*)d_in[3];
  float* out = (float*)d_out;

  int N = out_size / NCH;       // 50000
  int E = in_sizes[1] / 2;      // 800000

  char* ws = (char*)d_ws;
  size_t off = 0;
  auto alloc = [&](size_t bytes) -> char* {
    char* p = ws + off;
    off = (off + bytes + 255) & ~(size_t)255;
    return p;
  };
  char* zbase = ws;  // zero region: counts + flagsum (one small memset)
  int*                counts   = (int*)alloc((size_t)N * 4);
  unsigned long long* flagsum  = (unsigned long long*)alloc(1024);
  size_t zbytes = off;
  int*                row_ptr  = (int*)alloc((size_t)(N + 1) * 4);
  float*              dis      = (float*)alloc((size_t)N * 4);
  int*                rank     = (int*)alloc((size_t)E * 4);
  int*                edge_src = (int*)alloc((size_t)E * 4);
  unsigned short*     g        = (unsigned short*)alloc((size_t)N * NCH * 2);
  (void)ws_size;

  int nb   = (N + SCAN_CHUNK - 1) / SCAN_CHUNK;  // 25
  int gbl  = (N + GEMM_ROWS - 1) / GEMM_ROWS;    // 782 gemm blocks
  int cbl4 = (E + 1023) / 1024;                  // 782 count/fill blocks (4 edges/thr)

  (void)hipMemsetAsync(zbase, 0, zbytes, stream);
  k_gemm_count<<<gbl + cbl4, 256, 0, stream>>>(x, W, g, N, ei, E, counts, rank, gbl);
  k_scan<<<nb, 256, 0, stream>>>(counts, N, flagsum, row_ptr, dis);
  k_fill<<<cbl4, 256, 0, stream>>>(ei, E, rank, row_ptr, edge_src);
  k_agg<<<(N + 3) / 4, 256, 0, stream>>>(g, row_ptr, edge_src, dis, bias, out, N);
}